// Round 1
// baseline (411.813 us; speedup 1.0000x reference)
//
#include <hip/hip_runtime.h>
#include <hip/hip_bf16.h>

#define BATCH 32
#define SEQ   2048
#define DIM   1024

typedef __attribute__((ext_vector_type(4))) float f32x4;
typedef __attribute__((ext_vector_type(8))) short short8;

static __device__ __forceinline__ ushort f2bf(float x) {
    __hip_bfloat16 h = __float2bfloat16(x);
    union { __hip_bfloat16 h; ushort u; } cv; cv.h = h;
    return cv.u;
}

// ---------------- k0a: Wh f32 -> bf16 ----------------
__global__ __launch_bounds__(256) void kWhConv(const float* __restrict__ Wh,
                                               ushort* __restrict__ whb) {
    int i = (blockIdx.x * 256 + threadIdx.x) * 8;
    float4 a = *(const float4*)(Wh + i);
    float4 b = *(const float4*)(Wh + i + 4);
    union { ushort us[8]; uint4 u4; } pk;
    pk.us[0] = f2bf(a.x); pk.us[1] = f2bf(a.y); pk.us[2] = f2bf(a.z); pk.us[3] = f2bf(a.w);
    pk.us[4] = f2bf(b.x); pk.us[5] = f2bf(b.y); pk.us[6] = f2bf(b.z); pk.us[7] = f2bf(b.w);
    *(uint4*)(whb + i) = pk.u4;
}

// ---------------- k0b: base[b,e] = dec[b,:]·Ws[e,:] + bs + bh (+bc) ----------------
__global__ __launch_bounds__(256) void kBase(const float* __restrict__ dh,
                                             const float* __restrict__ Ws,
                                             const float* __restrict__ bs,
                                             const float* __restrict__ bh,
                                             const float* __restrict__ bc,
                                             const int* __restrict__ uc,
                                             float* __restrict__ base) {
    __shared__ float dec[8][DIM];
    int ec = blockIdx.x >> 2;   // 32 e-chunks of 32
    int bg = blockIdx.x & 3;    // 4 b-groups of 8
    int b0 = bg * 8, e0 = ec * 32;
    int tid = threadIdx.x;
    for (int i = tid; i < 8 * DIM; i += 256) {
        int bb = i >> 10, d = i & 1023;
        float vdec = (d < 512) ? dh[(b0 + bb) * 512 + d]
                               : dh[BATCH * 512 + (b0 + bb) * 512 + d - 512];
        dec[bb][d] = vdec;
    }
    __syncthreads();
    int el = tid >> 3, ds = tid & 7;
    int e = e0 + el;
    float acc[8] = {0.f, 0.f, 0.f, 0.f, 0.f, 0.f, 0.f, 0.f};
    const float* wrow = Ws + (size_t)e * DIM;
    for (int i = 0; i < 128; ++i) {
        int d = i * 8 + ds;
        float wv = wrow[d];
#pragma unroll
        for (int bb = 0; bb < 8; ++bb) acc[bb] += wv * dec[bb][d];
    }
#pragma unroll
    for (int bb = 0; bb < 8; ++bb) {
        float s = acc[bb];
        s += __shfl_xor(s, 1); s += __shfl_xor(s, 2); s += __shfl_xor(s, 4);
        acc[bb] = s;
    }
    if (ds == 0) {
        float bias = bs[e] + bh[e] + ((*uc) ? bc[e] : 0.0f);
#pragma unroll
        for (int bb = 0; bb < 8; ++bb) base[(b0 + bb) * DIM + e] = acc[bb] + bias;
    }
}

// ---------------- k2: fused GEMM(bf16 MFMA) + tanh + v-dot -> score ----------------
// block = 512 thr (8 waves). Block tile: 64 rows x full N=1024. Wave w: e in [w*128, w*128+128).
// A (enc rows) staged f32->bf16 into LDS, double-buffered, XOR-swizzled.
// B (Wh bf16) read straight from global (L2-resident 2 MB).
__global__ __launch_bounds__(512, 2) void kScore(const float* __restrict__ enc,
                                                 const ushort* __restrict__ whb,
                                                 const float* __restrict__ base,
                                                 const float* __restrict__ pc,
                                                 const float* __restrict__ Wc,
                                                 const float* __restrict__ vv,
                                                 const int* __restrict__ uc,
                                                 float* __restrict__ score) {
    __shared__ ushort lds[2][64 * 64];
    __shared__ float pcl[64];
    __shared__ float red[8][64];

    const int tid = threadIdx.x;
    const int w = tid >> 6;
    const int lane = tid & 63;
    const int q = lane >> 4, l15 = lane & 15;
    const int bx = blockIdx.x;
    const int b = bx >> 5;
    const int s0 = (bx & 31) << 6;

    const float* Ab = enc + ((size_t)(b * SEQ + s0)) * DIM;

    if (tid < 64) pcl[tid] = pc[b * SEQ + s0 + tid];

    const int srow = tid >> 3, sk8 = tid & 7;
    const float* gsrc = Ab + (size_t)srow * DIM + sk8 * 8;
    const int swidx = ((srow << 6) + (sk8 << 3)) ^ ((srow & 7) << 3);

    f32x4 acc[4][8] = {};

    // prologue: stage kt = 0
    {
        float4 a0 = *(const float4*)gsrc;
        float4 a1 = *(const float4*)(gsrc + 4);
        union { ushort us[8]; uint4 u4; } pk;
        pk.us[0] = f2bf(a0.x); pk.us[1] = f2bf(a0.y); pk.us[2] = f2bf(a0.z); pk.us[3] = f2bf(a0.w);
        pk.us[4] = f2bf(a1.x); pk.us[5] = f2bf(a1.y); pk.us[6] = f2bf(a1.z); pk.us[7] = f2bf(a1.w);
        *(uint4*)(&lds[0][swidx]) = pk.u4;
    }
    __syncthreads();

    const ushort* Bb = whb + (size_t)((w << 7) + l15) * DIM + (q << 3);

    for (int kt = 0; kt < 16; ++kt) {
        float4 a0, a1;
        if (kt < 15) {  // prefetch next A-tile to regs (overlaps MFMA below)
            a0 = *(const float4*)(gsrc + (kt + 1) * 64);
            a1 = *(const float4*)(gsrc + (kt + 1) * 64 + 4);
        }
        const ushort* Lb = lds[kt & 1];
#pragma unroll
        for (int kk = 0; kk < 64; kk += 32) {
            short8 af[4];
#pragma unroll
            for (int mf = 0; mf < 4; ++mf) {
                int idx = ((((mf << 4) + l15) << 6) + kk + (q << 3)) ^ ((l15 & 7) << 3);
                af[mf] = *(const short8*)(&Lb[idx]);
            }
#pragma unroll
            for (int ef = 0; ef < 8; ++ef) {
                short8 bf = *(const short8*)(Bb + (size_t)(ef << 4) * DIM + (kt << 6) + kk);
#pragma unroll
                for (int mf = 0; mf < 4; ++mf)
                    acc[mf][ef] = __builtin_amdgcn_mfma_f32_16x16x32_bf16(af[mf], bf, acc[mf][ef], 0, 0, 0);
            }
        }
        if (kt < 15) {
            union { ushort us[8]; uint4 u4; } pk;
            pk.us[0] = f2bf(a0.x); pk.us[1] = f2bf(a0.y); pk.us[2] = f2bf(a0.z); pk.us[3] = f2bf(a0.w);
            pk.us[4] = f2bf(a1.x); pk.us[5] = f2bf(a1.y); pk.us[6] = f2bf(a1.z); pk.us[7] = f2bf(a1.w);
            *(uint4*)(&lds[(kt + 1) & 1][swidx]) = pk.u4;
        }
        __syncthreads();
    }

    // epilogue: score_partial = sum_e tanh(acc + base + pc*Wc) * v[e]
    const float ucf = (float)(*uc);
    float basee[8], ve[8], wce[8];
#pragma unroll
    for (int ef = 0; ef < 8; ++ef) {
        int e = (w << 7) + (ef << 4) + l15;
        basee[ef] = base[b * DIM + e];
        ve[ef] = vv[e];
        wce[ef] = Wc[e] * ucf;
    }
#pragma unroll
    for (int mf = 0; mf < 4; ++mf) {
#pragma unroll
        for (int r = 0; r < 4; ++r) {
            int rl = (mf << 4) + (q << 2) + r;
            float p = pcl[rl];
            float sp = 0.f;
#pragma unroll
            for (int ef = 0; ef < 8; ++ef)
                sp += tanhf(acc[mf][ef][r] + basee[ef] + p * wce[ef]) * ve[ef];
            sp += __shfl_xor(sp, 1);
            sp += __shfl_xor(sp, 2);
            sp += __shfl_xor(sp, 4);
            sp += __shfl_xor(sp, 8);
            if (l15 == 0) red[w][rl] = sp;
        }
    }
    __syncthreads();
    if (tid < 64) {
        float s = 0.f;
#pragma unroll
        for (int ww = 0; ww < 8; ++ww) s += red[ww][tid];
        score[b * SEQ + s0 + tid] = s;  // bv dropped: softmax shift-invariant
    }
}

// ---------------- k3: softmax + mask + renorm + coverage ----------------
__global__ __launch_bounds__(512) void kSoftmax(const float* __restrict__ score,
                                                const float* __restrict__ mask,
                                                const float* __restrict__ pc,
                                                float* __restrict__ att,
                                                float* __restrict__ cov,
                                                int write_cov) {
    __shared__ float rmax[8], rsum[8];
    int b = blockIdx.x, tid = threadIdx.x;
    int wv = tid >> 6, ln = tid & 63;
    float x[4];
#pragma unroll
    for (int i = 0; i < 4; ++i) x[i] = score[b * SEQ + tid + i * 512];
    float m = fmaxf(fmaxf(x[0], x[1]), fmaxf(x[2], x[3]));
#pragma unroll
    for (int o = 1; o < 64; o <<= 1) m = fmaxf(m, __shfl_xor(m, o));
    if (ln == 0) rmax[wv] = m;
    __syncthreads();
    m = rmax[0];
#pragma unroll
    for (int i = 1; i < 8; ++i) m = fmaxf(m, rmax[i]);

    // e^(x-m) * mask ; S1 cancels in the renormalization so skip it
    float ms[4], wm[4];
#pragma unroll
    for (int i = 0; i < 4; ++i) ms[i] = mask[b * SEQ + tid + i * 512];
    float s = 0.f;
#pragma unroll
    for (int i = 0; i < 4; ++i) { wm[i] = __expf(x[i] - m) * ms[i]; s += wm[i]; }
#pragma unroll
    for (int o = 1; o < 64; o <<= 1) s += __shfl_xor(s, o);
    if (ln == 0) rsum[wv] = s;
    __syncthreads();
    s = 0.f;
#pragma unroll
    for (int i = 0; i < 8; ++i) s += rsum[i];
    float inv = 1.0f / s;
#pragma unroll
    for (int i = 0; i < 4; ++i) {
        float wf = wm[i] * inv;
        att[b * SEQ + tid + i * 512] = wf;
        if (write_cov) cov[b * SEQ + tid + i * 512] = pc[b * SEQ + tid + i * 512] + wf;
    }
}

// ---------------- k4: context partials over s-chunks ----------------
__global__ __launch_bounds__(256) void kCtxPart(const float* __restrict__ enc,
                                                const float* __restrict__ att,
                                                float* __restrict__ part) {
    __shared__ float wl[64];
    int bx = blockIdx.x;           // 32 b x 32 s-chunks
    int b = bx >> 5, sc = bx & 31;
    int tid = threadIdx.x;
    if (tid < 64) wl[tid] = att[b * SEQ + sc * 64 + tid];
    __syncthreads();
    const float* basep = enc + ((size_t)(b * SEQ + sc * 64)) * DIM + tid * 4;
    float4 acc = {0.f, 0.f, 0.f, 0.f};
#pragma unroll 4
    for (int i = 0; i < 64; ++i) {
        float w = wl[i];
        float4 xv = *(const float4*)(basep + (size_t)i * DIM);
        acc.x += w * xv.x; acc.y += w * xv.y; acc.z += w * xv.z; acc.w += w * xv.w;
    }
    *(float4*)(part + (size_t)bx * DIM + tid * 4) = acc;
}

// ---------------- k5: deterministic reduce of partials ----------------
__global__ __launch_bounds__(256) void kCtxReduce(const float* __restrict__ part,
                                                  float* __restrict__ ctx) {
    int g = blockIdx.x * 256 + threadIdx.x;  // 32768
    int b = g >> 10, d = g & 1023;
    float s = 0.f;
#pragma unroll
    for (int i = 0; i < 32; ++i) s += part[((size_t)(b * 32 + i) << 10) + d];
    ctx[g] = s;
}

extern "C" void kernel_launch(void* const* d_in, const int* in_sizes, int n_in,
                              void* d_out, int out_size, void* d_ws, size_t ws_size,
                              hipStream_t stream) {
    const float* dh   = (const float*)d_in[0];
    const float* enc  = (const float*)d_in[1];
    const float* mask = (const float*)d_in[2];
    const float* pc   = (const float*)d_in[3];
    const float* Wh   = (const float*)d_in[4];
    const float* bh   = (const float*)d_in[5];
    const float* Ws   = (const float*)d_in[6];
    const float* bs   = (const float*)d_in[7];
    const float* Wc   = (const float*)d_in[8];
    const float* bc   = (const float*)d_in[9];
    const float* vv   = (const float*)d_in[10];
    // d_in[11] = bv: uniform shift of scores -> softmax-invariant -> unused
    const int* uc     = (const int*)d_in[12];

    float* ctx = (float*)d_out;
    float* att = ctx + BATCH * DIM;
    float* cov = att + BATCH * SEQ;
    int write_cov = (out_size >= BATCH * (DIM + 2 * SEQ)) ? 1 : 0;

    ushort* whb  = (ushort*)d_ws;                                   // 2 MB
    float* base  = (float*)((char*)d_ws + 2u * 1024u * 1024u);      // 128 KB
    float* score = base + BATCH * DIM;                              // 256 KB
    float* part  = score + BATCH * SEQ;                             // 4 MB

    kWhConv<<<512, 256, 0, stream>>>(Wh, whb);
    kBase<<<128, 256, 0, stream>>>(dh, Ws, bs, bh, bc, uc, base);
    kScore<<<1024, 512, 0, stream>>>(enc, whb, base, pc, Wc, vv, uc, score);
    kSoftmax<<<BATCH, 512, 0, stream>>>(score, mask, pc, att, cov, write_cov);
    kCtxPart<<<1024, 256, 0, stream>>>(enc, att, part);
    kCtxReduce<<<128, 256, 0, stream>>>(part, ctx);
}

// Round 2
// 384.798 us; speedup vs baseline: 1.0702x; 1.0702x over previous
//
#include <hip/hip_runtime.h>
#include <hip/hip_bf16.h>

#define BATCH 32
#define SEQ   2048
#define DIM   1024

typedef __attribute__((ext_vector_type(4))) float f32x4;
typedef __attribute__((ext_vector_type(8))) short short8;

static __device__ __forceinline__ ushort f2bf(float x) {
    __hip_bfloat16 h = __float2bfloat16(x);
    union { __hip_bfloat16 h; ushort u; } cv; cv.h = h;
    return cv.u;
}

// ---------------- k0a: Wh f32 -> bf16 ----------------
__global__ __launch_bounds__(256) void kWhConv(const float* __restrict__ Wh,
                                               ushort* __restrict__ whb) {
    int i = (blockIdx.x * 256 + threadIdx.x) * 8;
    float4 a = *(const float4*)(Wh + i);
    float4 b = *(const float4*)(Wh + i + 4);
    union { ushort us[8]; uint4 u4; } pk;
    pk.us[0] = f2bf(a.x); pk.us[1] = f2bf(a.y); pk.us[2] = f2bf(a.z); pk.us[3] = f2bf(a.w);
    pk.us[4] = f2bf(b.x); pk.us[5] = f2bf(b.y); pk.us[6] = f2bf(b.z); pk.us[7] = f2bf(b.w);
    *(uint4*)(whb + i) = pk.u4;
}

// ---------------- k0b: base[b,e] = dec[b,:]·Ws[e,:] + bs + bh (+bc) ----------------
__global__ __launch_bounds__(256) void kBase(const float* __restrict__ dh,
                                             const float* __restrict__ Ws,
                                             const float* __restrict__ bs,
                                             const float* __restrict__ bh,
                                             const float* __restrict__ bc,
                                             const int* __restrict__ uc,
                                             float* __restrict__ base) {
    __shared__ float dec[8][DIM];
    int ec = blockIdx.x >> 2;   // 32 e-chunks of 32
    int bg = blockIdx.x & 3;    // 4 b-groups of 8
    int b0 = bg * 8, e0 = ec * 32;
    int tid = threadIdx.x;
    for (int i = tid; i < 8 * DIM; i += 256) {
        int bb = i >> 10, d = i & 1023;
        float vdec = (d < 512) ? dh[(b0 + bb) * 512 + d]
                               : dh[BATCH * 512 + (b0 + bb) * 512 + d - 512];
        dec[bb][d] = vdec;
    }
    __syncthreads();
    int el = tid >> 3, ds = tid & 7;
    int e = e0 + el;
    float acc[8] = {0.f, 0.f, 0.f, 0.f, 0.f, 0.f, 0.f, 0.f};
    const float* wrow = Ws + (size_t)e * DIM;
    for (int i = 0; i < 128; ++i) {
        int d = i * 8 + ds;
        float wv = wrow[d];
#pragma unroll
        for (int bb = 0; bb < 8; ++bb) acc[bb] += wv * dec[bb][d];
    }
#pragma unroll
    for (int bb = 0; bb < 8; ++bb) {
        float s = acc[bb];
        s += __shfl_xor(s, 1); s += __shfl_xor(s, 2); s += __shfl_xor(s, 4);
        acc[bb] = s;
    }
    if (ds == 0) {
        float bias = bs[e] + bh[e] + ((*uc) ? bc[e] : 0.0f);
#pragma unroll
        for (int bb = 0; bb < 8; ++bb) base[(b0 + bb) * DIM + e] = acc[bb] + bias;
    }
}

// ---------------- k2: fused GEMM(bf16 MFMA) + tanh + v-dot -> score ----------------
// block = 1024 thr (16 waves). Block tile: 64 rows x full N=1024; wave w: 64 cols.
// BK=128, double-buffered LDS, XOR-swizzled. acc = 4x4 f32x4 = 64 VGPR -> 4 waves/SIMD.
__global__ __launch_bounds__(1024, 4) void kScore(const float* __restrict__ enc,
                                                  const ushort* __restrict__ whb,
                                                  const float* __restrict__ base,
                                                  const float* __restrict__ pc,
                                                  const float* __restrict__ Wc,
                                                  const float* __restrict__ vv,
                                                  const int* __restrict__ uc,
                                                  float* __restrict__ score) {
    __shared__ ushort lds[2][64 * 128];
    __shared__ float pcl[64];
    __shared__ float red[16][64];

    const int tid = threadIdx.x;
    const int w = tid >> 6;
    const int lane = tid & 63;
    const int q = lane >> 4, l15 = lane & 15;
    const int bx = blockIdx.x;
    const int b = bx >> 5;
    const int s0 = (bx & 31) << 6;

    const float* Ab = enc + ((size_t)(b * SEQ + s0)) * DIM;
    if (tid < 64) pcl[tid] = pc[b * SEQ + s0 + tid];

    // staging: thread t stages 8 elems of row srow at k-offset sk (within BK=128 slice)
    const int srow = tid >> 4;
    const int sk = (tid & 15) << 3;
    const int swidx = srow * 128 + (sk ^ ((srow & 7) << 3));
    const float* gsrc = Ab + (size_t)srow * DIM + sk;

    f32x4 acc[4][4] = {};

    // prologue: stage kt = 0
    {
        float4 a0 = *(const float4*)gsrc;
        float4 a1 = *(const float4*)(gsrc + 4);
        union { ushort us[8]; uint4 u4; } pk;
        pk.us[0] = f2bf(a0.x); pk.us[1] = f2bf(a0.y); pk.us[2] = f2bf(a0.z); pk.us[3] = f2bf(a0.w);
        pk.us[4] = f2bf(a1.x); pk.us[5] = f2bf(a1.y); pk.us[6] = f2bf(a1.z); pk.us[7] = f2bf(a1.w);
        *(uint4*)(&lds[0][swidx]) = pk.u4;
    }
    __syncthreads();

    const ushort* Bw = whb + (size_t)((w << 6) + l15) * DIM + (q << 3);

    for (int kt = 0; kt < 8; ++kt) {
        float4 a0, a1;
        if (kt < 7) {  // prefetch next f32 slice to regs; consumed after MFMA phase
            a0 = *(const float4*)(gsrc + (kt + 1) * 128);
            a1 = *(const float4*)(gsrc + (kt + 1) * 128 + 4);
        }
        const ushort* Lb = lds[kt & 1];
#pragma unroll
        for (int kk = 0; kk < 128; kk += 32) {
            short8 af[4];
#pragma unroll
            for (int mf = 0; mf < 4; ++mf) {
                int idx = ((mf << 4) + l15) * 128 + ((kk + (q << 3)) ^ ((l15 & 7) << 3));
                af[mf] = *(const short8*)(&Lb[idx]);
            }
#pragma unroll
            for (int ef = 0; ef < 4; ++ef) {
                short8 bf = *(const short8*)(Bw + (size_t)(ef << 4) * DIM + (kt << 7) + kk);
#pragma unroll
                for (int mf = 0; mf < 4; ++mf)
                    acc[mf][ef] = __builtin_amdgcn_mfma_f32_16x16x32_bf16(af[mf], bf, acc[mf][ef], 0, 0, 0);
            }
        }
        if (kt < 7) {
            union { ushort us[8]; uint4 u4; } pk;
            pk.us[0] = f2bf(a0.x); pk.us[1] = f2bf(a0.y); pk.us[2] = f2bf(a0.z); pk.us[3] = f2bf(a0.w);
            pk.us[4] = f2bf(a1.x); pk.us[5] = f2bf(a1.y); pk.us[6] = f2bf(a1.z); pk.us[7] = f2bf(a1.w);
            *(uint4*)(&lds[(kt + 1) & 1][swidx]) = pk.u4;
        }
        __syncthreads();
    }

    // epilogue: score_partial = sum_e tanh(acc + base + pc*Wc) * v[e]
    const float ucf = (float)(*uc);
    float basee[4], ve[4], wce[4];
#pragma unroll
    for (int ef = 0; ef < 4; ++ef) {
        int e = (w << 6) + (ef << 4) + l15;
        basee[ef] = base[b * DIM + e];
        ve[ef] = vv[e];
        wce[ef] = Wc[e] * ucf;
    }
#pragma unroll
    for (int mf = 0; mf < 4; ++mf) {
#pragma unroll
        for (int r = 0; r < 4; ++r) {
            int rl = (mf << 4) + (q << 2) + r;
            float p = pcl[rl];
            float sp = 0.f;
#pragma unroll
            for (int ef = 0; ef < 4; ++ef) {
                float x = acc[mf][ef][r] + basee[ef] + p * wce[ef];
                // tanh(x) = 1 - 2/(1+e^{2x}); exact at +/-inf, ~1e-7 abs err
                float t = 1.0f - 2.0f / (1.0f + __expf(2.0f * x));
                sp += t * ve[ef];
            }
            sp += __shfl_xor(sp, 1);
            sp += __shfl_xor(sp, 2);
            sp += __shfl_xor(sp, 4);
            sp += __shfl_xor(sp, 8);
            if (l15 == 0) red[w][rl] = sp;
        }
    }
    __syncthreads();
    if (tid < 64) {
        float s = 0.f;
#pragma unroll
        for (int ww = 0; ww < 16; ++ww) s += red[ww][tid];
        score[b * SEQ + s0 + tid] = s;  // bv dropped: softmax shift-invariant
    }
}

// ---------------- k3: softmax + mask + renorm + coverage ----------------
__global__ __launch_bounds__(512) void kSoftmax(const float* __restrict__ score,
                                                const float* __restrict__ mask,
                                                const float* __restrict__ pc,
                                                float* __restrict__ att,
                                                float* __restrict__ cov,
                                                int write_cov) {
    __shared__ float rmax[8], rsum[8];
    int b = blockIdx.x, tid = threadIdx.x;
    int wv = tid >> 6, ln = tid & 63;
    float x[4];
#pragma unroll
    for (int i = 0; i < 4; ++i) x[i] = score[b * SEQ + tid + i * 512];
    float m = fmaxf(fmaxf(x[0], x[1]), fmaxf(x[2], x[3]));
#pragma unroll
    for (int o = 1; o < 64; o <<= 1) m = fmaxf(m, __shfl_xor(m, o));
    if (ln == 0) rmax[wv] = m;
    __syncthreads();
    m = rmax[0];
#pragma unroll
    for (int i = 1; i < 8; ++i) m = fmaxf(m, rmax[i]);

    float ms[4], wm[4];
#pragma unroll
    for (int i = 0; i < 4; ++i) ms[i] = mask[b * SEQ + tid + i * 512];
    float s = 0.f;
#pragma unroll
    for (int i = 0; i < 4; ++i) { wm[i] = __expf(x[i] - m) * ms[i]; s += wm[i]; }
#pragma unroll
    for (int o = 1; o < 64; o <<= 1) s += __shfl_xor(s, o);
    if (ln == 0) rsum[wv] = s;
    __syncthreads();
    s = 0.f;
#pragma unroll
    for (int i = 0; i < 8; ++i) s += rsum[i];
    float inv = 1.0f / s;
#pragma unroll
    for (int i = 0; i < 4; ++i) {
        float wf = wm[i] * inv;
        att[b * SEQ + tid + i * 512] = wf;
        if (write_cov) cov[b * SEQ + tid + i * 512] = pc[b * SEQ + tid + i * 512] + wf;
    }
}

// ---------------- k4: context partials over s-chunks ----------------
__global__ __launch_bounds__(256) void kCtxPart(const float* __restrict__ enc,
                                                const float* __restrict__ att,
                                                float* __restrict__ part) {
    __shared__ float wl[64];
    int bx = blockIdx.x;           // 32 b x 32 s-chunks
    int b = bx >> 5, sc = bx & 31;
    int tid = threadIdx.x;
    if (tid < 64) wl[tid] = att[b * SEQ + sc * 64 + tid];
    __syncthreads();
    const float* basep = enc + ((size_t)(b * SEQ + sc * 64)) * DIM + tid * 4;
    float4 acc = {0.f, 0.f, 0.f, 0.f};
#pragma unroll 4
    for (int i = 0; i < 64; ++i) {
        float w = wl[i];
        float4 xv = *(const float4*)(basep + (size_t)i * DIM);
        acc.x += w * xv.x; acc.y += w * xv.y; acc.z += w * xv.z; acc.w += w * xv.w;
    }
    *(float4*)(part + (size_t)bx * DIM + tid * 4) = acc;
}

// ---------------- k5: deterministic reduce of partials ----------------
__global__ __launch_bounds__(256) void kCtxReduce(const float* __restrict__ part,
                                                  float* __restrict__ ctx) {
    int g = blockIdx.x * 256 + threadIdx.x;  // 32768
    int b = g >> 10, d = g & 1023;
    float s = 0.f;
#pragma unroll
    for (int i = 0; i < 32; ++i) s += part[((size_t)(b * 32 + i) << 10) + d];
    ctx[g] = s;
}

extern "C" void kernel_launch(void* const* d_in, const int* in_sizes, int n_in,
                              void* d_out, int out_size, void* d_ws, size_t ws_size,
                              hipStream_t stream) {
    const float* dh   = (const float*)d_in[0];
    const float* enc  = (const float*)d_in[1];
    const float* mask = (const float*)d_in[2];
    const float* pc   = (const float*)d_in[3];
    const float* Wh   = (const float*)d_in[4];
    const float* bh   = (const float*)d_in[5];
    const float* Ws   = (const float*)d_in[6];
    const float* bs   = (const float*)d_in[7];
    const float* Wc   = (const float*)d_in[8];
    const float* bc   = (const float*)d_in[9];
    const float* vv   = (const float*)d_in[10];
    // d_in[11] = bv: uniform shift of scores -> softmax-invariant -> unused
    const int* uc     = (const int*)d_in[12];

    float* ctx = (float*)d_out;
    float* att = ctx + BATCH * DIM;
    float* cov = att + BATCH * SEQ;
    int write_cov = (out_size >= BATCH * (DIM + 2 * SEQ)) ? 1 : 0;

    ushort* whb  = (ushort*)d_ws;                                   // 2 MB
    float* base  = (float*)((char*)d_ws + 2u * 1024u * 1024u);      // 128 KB
    float* score = base + BATCH * DIM;                              // 256 KB
    float* part  = score + BATCH * SEQ;                             // 4 MB

    kWhConv<<<512, 256, 0, stream>>>(Wh, whb);
    kBase<<<128, 256, 0, stream>>>(dh, Ws, bs, bh, bc, uc, base);
    kScore<<<1024, 1024, 0, stream>>>(enc, whb, base, pc, Wc, vv, uc, score);
    kSoftmax<<<BATCH, 512, 0, stream>>>(score, mask, pc, att, cov, write_cov);
    kCtxPart<<<1024, 256, 0, stream>>>(enc, att, part);
    kCtxReduce<<<128, 256, 0, stream>>>(part, ctx);
}

// Round 3
// 281.127 us; speedup vs baseline: 1.4649x; 1.3688x over previous
//
#include <hip/hip_runtime.h>
#include <hip/hip_bf16.h>

#define BATCH 32
#define SEQ   2048
#define DIM   1024

typedef __attribute__((ext_vector_type(4))) float f32x4;
typedef __attribute__((ext_vector_type(8))) short short8;

static __device__ __forceinline__ ushort f2bf(float x) {
    __hip_bfloat16 h = __float2bfloat16(x);
    union { __hip_bfloat16 h; ushort u; } cv; cv.h = h;
    return cv.u;
}

// ---------------- k0a: Wh f32 -> bf16, packed in MFMA B-fragment order ----------------
// whbp[((eb*32 + kb)*64 + lane)*8 + j] = bf16( Wh[eb*16 + (lane&15)][kb*32 + (lane>>4)*8 + j] )
// so a wave's B-fragment load is base + lane*16B : fully coalesced 1KB.
__global__ __launch_bounds__(256) void kWhPack(const float* __restrict__ Wh,
                                               ushort* __restrict__ whbp) {
    int g = blockIdx.x * 256 + threadIdx.x;      // 131072 total
    int l  = g & 63;
    int kb = (g >> 6) & 31;
    int eb = g >> 11;
    int e  = eb * 16 + (l & 15);
    int k0 = kb * 32 + (l >> 4) * 8;
    const float* src = Wh + (size_t)e * DIM + k0;
    float4 a = *(const float4*)src;
    float4 b = *(const float4*)(src + 4);
    union { ushort us[8]; uint4 u4; } pk;
    pk.us[0] = f2bf(a.x); pk.us[1] = f2bf(a.y); pk.us[2] = f2bf(a.z); pk.us[3] = f2bf(a.w);
    pk.us[4] = f2bf(b.x); pk.us[5] = f2bf(b.y); pk.us[6] = f2bf(b.z); pk.us[7] = f2bf(b.w);
    *(uint4*)(whbp + (size_t)g * 8) = pk.u4;
}

// ---------------- k0b: base[b,e] = dec[b,:]·Ws[e,:] + bs + bh (+bc) ----------------
__global__ __launch_bounds__(256) void kBase(const float* __restrict__ dh,
                                             const float* __restrict__ Ws,
                                             const float* __restrict__ bs,
                                             const float* __restrict__ bh,
                                             const float* __restrict__ bc,
                                             const int* __restrict__ uc,
                                             float* __restrict__ base) {
    __shared__ float dec[8][DIM];
    int ec = blockIdx.x >> 2;
    int bg = blockIdx.x & 3;
    int b0 = bg * 8, e0 = ec * 32;
    int tid = threadIdx.x;
    for (int i = tid; i < 8 * DIM; i += 256) {
        int bb = i >> 10, d = i & 1023;
        float vdec = (d < 512) ? dh[(b0 + bb) * 512 + d]
                               : dh[BATCH * 512 + (b0 + bb) * 512 + d - 512];
        dec[bb][d] = vdec;
    }
    __syncthreads();
    int el = tid >> 3, ds = tid & 7;
    int e = e0 + el;
    float acc[8] = {0.f, 0.f, 0.f, 0.f, 0.f, 0.f, 0.f, 0.f};
    const float* wrow = Ws + (size_t)e * DIM;
    for (int i = 0; i < 128; ++i) {
        int d = i * 8 + ds;
        float wv = wrow[d];
#pragma unroll
        for (int bb = 0; bb < 8; ++bb) acc[bb] += wv * dec[bb][d];
    }
#pragma unroll
    for (int bb = 0; bb < 8; ++bb) {
        float s = acc[bb];
        s += __shfl_xor(s, 1); s += __shfl_xor(s, 2); s += __shfl_xor(s, 4);
        acc[bb] = s;
    }
    if (ds == 0) {
        float bias = bs[e] + bh[e] + ((*uc) ? bc[e] : 0.0f);
#pragma unroll
        for (int bb = 0; bb < 8; ++bb) base[(b0 + bb) * DIM + e] = acc[bb] + bias;
    }
}

// ---------------- k2: fused GEMM(bf16 MFMA) + tanh + v-dot -> score ----------------
// block = 1024 thr (16 waves). Block tile: 64 rows x full N=1024; wave w: 64 cols.
// BK=128 double-buffered LDS, full 4-bit XOR swizzle. B read coalesced from packed whbp (L2).
__global__ __launch_bounds__(1024, 4) void kScore(const float* __restrict__ enc,
                                                  const ushort* __restrict__ whbp,
                                                  const float* __restrict__ base,
                                                  const float* __restrict__ pc,
                                                  const float* __restrict__ Wc,
                                                  const float* __restrict__ vv,
                                                  const int* __restrict__ uc,
                                                  float* __restrict__ score) {
    __shared__ ushort lds[2][64 * 128];
    __shared__ float pcl[64];
    __shared__ float red[16][64];

    const int tid = threadIdx.x;
    const int w = tid >> 6;
    const int lane = tid & 63;
    const int q = lane >> 4, l15 = lane & 15;
    const int bx = blockIdx.x;
    const int b = bx >> 5;
    const int s0 = (bx & 31) << 6;

    const float* Ab = enc + ((size_t)(b * SEQ + s0)) * DIM;
    if (tid < 64) pcl[tid] = pc[b * SEQ + s0 + tid];

    // staging: thread t stages 8 elems of row srow at slot (tid&15), swizzled by row&15
    const int srow = tid >> 4;
    const int sslot = tid & 15;
    const int swidx = srow * 128 + (((sslot ^ (srow & 15))) << 3);
    const float* gsrc = Ab + (size_t)srow * DIM + (sslot << 3);

    f32x4 acc[4][4] = {};

    // prologue: stage kt = 0
    {
        float4 a0 = *(const float4*)gsrc;
        float4 a1 = *(const float4*)(gsrc + 4);
        union { ushort us[8]; uint4 u4; } pk;
        pk.us[0] = f2bf(a0.x); pk.us[1] = f2bf(a0.y); pk.us[2] = f2bf(a0.z); pk.us[3] = f2bf(a0.w);
        pk.us[4] = f2bf(a1.x); pk.us[5] = f2bf(a1.y); pk.us[6] = f2bf(a1.z); pk.us[7] = f2bf(a1.w);
        *(uint4*)(&lds[0][swidx]) = pk.u4;
    }
    __syncthreads();

    for (int kt = 0; kt < 8; ++kt) {
        float4 a0, a1;
        if (kt < 7) {  // prefetch next f32 slice to regs; consumed after MFMA phase
            a0 = *(const float4*)(gsrc + (kt + 1) * 128);
            a1 = *(const float4*)(gsrc + (kt + 1) * 128 + 4);
        }
        const ushort* Lb = lds[kt & 1];
#pragma unroll
        for (int kk = 0; kk < 128; kk += 32) {
            // B fragments: coalesced 1KB wave loads from packed layout (L2-resident)
            short8 bfr[4];
#pragma unroll
            for (int ef = 0; ef < 4; ++ef) {
                int fidx = (((w << 2) + ef) << 5) + (kt << 2) + (kk >> 5);  // (eb*32 + kb)
                bfr[ef] = *(const short8*)(whbp + ((size_t)fidx << 9) + (lane << 3));
            }
            short8 af[4];
#pragma unroll
            for (int mf = 0; mf < 4; ++mf) {
                int idx = ((mf << 4) + l15) * 128 + ((kk + (q << 3)) ^ (l15 << 3));
                af[mf] = *(const short8*)(&Lb[idx]);
            }
#pragma unroll
            for (int ef = 0; ef < 4; ++ef)
#pragma unroll
                for (int mf = 0; mf < 4; ++mf)
                    acc[mf][ef] = __builtin_amdgcn_mfma_f32_16x16x32_bf16(af[mf], bfr[ef], acc[mf][ef], 0, 0, 0);
        }
        if (kt < 7) {
            union { ushort us[8]; uint4 u4; } pk;
            pk.us[0] = f2bf(a0.x); pk.us[1] = f2bf(a0.y); pk.us[2] = f2bf(a0.z); pk.us[3] = f2bf(a0.w);
            pk.us[4] = f2bf(a1.x); pk.us[5] = f2bf(a1.y); pk.us[6] = f2bf(a1.z); pk.us[7] = f2bf(a1.w);
            *(uint4*)(&lds[(kt + 1) & 1][swidx]) = pk.u4;
        }
        __syncthreads();
    }

    // epilogue: score_partial = sum_e tanh(acc + base + pc*Wc) * v[e]
    const float ucf = (float)(*uc);
    float basee[4], ve[4], wce[4];
#pragma unroll
    for (int ef = 0; ef < 4; ++ef) {
        int e = (w << 6) + (ef << 4) + l15;
        basee[ef] = base[b * DIM + e];
        ve[ef] = vv[e];
        wce[ef] = Wc[e] * ucf;
    }
#pragma unroll
    for (int mf = 0; mf < 4; ++mf) {
#pragma unroll
        for (int r = 0; r < 4; ++r) {
            int rl = (mf << 4) + (q << 2) + r;
            float p = pcl[rl];
            float sp = 0.f;
#pragma unroll
            for (int ef = 0; ef < 4; ++ef) {
                float x = acc[mf][ef][r] + basee[ef] + p * wce[ef];
                float t = 1.0f - 2.0f / (1.0f + __expf(2.0f * x));  // tanh
                sp += t * ve[ef];
            }
            sp += __shfl_xor(sp, 1);
            sp += __shfl_xor(sp, 2);
            sp += __shfl_xor(sp, 4);
            sp += __shfl_xor(sp, 8);
            if (l15 == 0) red[w][rl] = sp;
        }
    }
    __syncthreads();
    if (tid < 64) {
        float s = 0.f;
#pragma unroll
        for (int ww = 0; ww < 16; ++ww) s += red[ww][tid];
        score[b * SEQ + s0 + tid] = s;  // bv dropped: softmax shift-invariant
    }
}

// ---------------- k3: softmax + mask + renorm + coverage ----------------
__global__ __launch_bounds__(512) void kSoftmax(const float* __restrict__ score,
                                                const float* __restrict__ mask,
                                                const float* __restrict__ pc,
                                                float* __restrict__ att,
                                                float* __restrict__ cov,
                                                int write_cov) {
    __shared__ float rmax[8], rsum[8];
    int b = blockIdx.x, tid = threadIdx.x;
    int wv = tid >> 6, ln = tid & 63;
    float x[4];
#pragma unroll
    for (int i = 0; i < 4; ++i) x[i] = score[b * SEQ + tid + i * 512];
    float m = fmaxf(fmaxf(x[0], x[1]), fmaxf(x[2], x[3]));
#pragma unroll
    for (int o = 1; o < 64; o <<= 1) m = fmaxf(m, __shfl_xor(m, o));
    if (ln == 0) rmax[wv] = m;
    __syncthreads();
    m = rmax[0];
#pragma unroll
    for (int i = 1; i < 8; ++i) m = fmaxf(m, rmax[i]);

    float ms[4], wm[4];
#pragma unroll
    for (int i = 0; i < 4; ++i) ms[i] = mask[b * SEQ + tid + i * 512];
    float s = 0.f;
#pragma unroll
    for (int i = 0; i < 4; ++i) { wm[i] = __expf(x[i] - m) * ms[i]; s += wm[i]; }
#pragma unroll
    for (int o = 1; o < 64; o <<= 1) s += __shfl_xor(s, o);
    if (ln == 0) rsum[wv] = s;
    __syncthreads();
    s = 0.f;
#pragma unroll
    for (int i = 0; i < 8; ++i) s += rsum[i];
    float inv = 1.0f / s;
#pragma unroll
    for (int i = 0; i < 4; ++i) {
        float wf = wm[i] * inv;
        att[b * SEQ + tid + i * 512] = wf;
        if (write_cov) cov[b * SEQ + tid + i * 512] = pc[b * SEQ + tid + i * 512] + wf;
    }
}

// ---------------- k4: context partials over s-chunks ----------------
__global__ __launch_bounds__(256) void kCtxPart(const float* __restrict__ enc,
                                                const float* __restrict__ att,
                                                float* __restrict__ part) {
    __shared__ float wl[64];
    int bx = blockIdx.x;           // 32 b x 32 s-chunks
    int b = bx >> 5, sc = bx & 31;
    int tid = threadIdx.x;
    if (tid < 64) wl[tid] = att[b * SEQ + sc * 64 + tid];
    __syncthreads();
    const float* basep = enc + ((size_t)(b * SEQ + sc * 64)) * DIM + tid * 4;
    float4 acc = {0.f, 0.f, 0.f, 0.f};
#pragma unroll 4
    for (int i = 0; i < 64; ++i) {
        float w = wl[i];
        float4 xv = *(const float4*)(basep + (size_t)i * DIM);
        acc.x += w * xv.x; acc.y += w * xv.y; acc.z += w * xv.z; acc.w += w * xv.w;
    }
    *(float4*)(part + (size_t)bx * DIM + tid * 4) = acc;
}

// ---------------- k5: deterministic reduce of partials ----------------
__global__ __launch_bounds__(256) void kCtxReduce(const float* __restrict__ part,
                                                  float* __restrict__ ctx) {
    int g = blockIdx.x * 256 + threadIdx.x;  // 32768
    int b = g >> 10, d = g & 1023;
    float s = 0.f;
#pragma unroll
    for (int i = 0; i < 32; ++i) s += part[((size_t)(b * 32 + i) << 10) + d];
    ctx[g] = s;
}

extern "C" void kernel_launch(void* const* d_in, const int* in_sizes, int n_in,
                              void* d_out, int out_size, void* d_ws, size_t ws_size,
                              hipStream_t stream) {
    const float* dh   = (const float*)d_in[0];
    const float* enc  = (const float*)d_in[1];
    const float* mask = (const float*)d_in[2];
    const float* pc   = (const float*)d_in[3];
    const float* Wh   = (const float*)d_in[4];
    const float* bh   = (const float*)d_in[5];
    const float* Ws   = (const float*)d_in[6];
    const float* bs   = (const float*)d_in[7];
    const float* Wc   = (const float*)d_in[8];
    const float* bc   = (const float*)d_in[9];
    const float* vv   = (const float*)d_in[10];
    // d_in[11] = bv: uniform shift of scores -> softmax-invariant -> unused
    const int* uc     = (const int*)d_in[12];

    float* ctx = (float*)d_out;
    float* att = ctx + BATCH * DIM;
    float* cov = att + BATCH * SEQ;
    int write_cov = (out_size >= BATCH * (DIM + 2 * SEQ)) ? 1 : 0;

    ushort* whbp = (ushort*)d_ws;                                   // 2 MB (packed)
    float* base  = (float*)((char*)d_ws + 2u * 1024u * 1024u);      // 128 KB
    float* score = base + BATCH * DIM;                              // 256 KB
    float* part  = score + BATCH * SEQ;                             // 4 MB

    kWhPack<<<512, 256, 0, stream>>>(Wh, whbp);
    kBase<<<128, 256, 0, stream>>>(dh, Ws, bs, bh, bc, uc, base);
    kScore<<<1024, 1024, 0, stream>>>(enc, whbp, base, pc, Wc, vv, uc, score);
    kSoftmax<<<BATCH, 512, 0, stream>>>(score, mask, pc, att, cov, write_cov);
    kCtxPart<<<1024, 256, 0, stream>>>(enc, att, part);
    kCtxReduce<<<128, 256, 0, stream>>>(part, ctx);
}

// Round 4
// 270.471 us; speedup vs baseline: 1.5226x; 1.0394x over previous
//
#include <hip/hip_runtime.h>
#include <hip/hip_bf16.h>

#define BATCH 32
#define SEQ   2048
#define DIM   1024

typedef __attribute__((ext_vector_type(4))) float f32x4;
typedef __attribute__((ext_vector_type(8))) short short8;
typedef __attribute__((ext_vector_type(4))) ushort u16x4;

static __device__ __forceinline__ ushort f2bf(float x) {
    __hip_bfloat16 h = __float2bfloat16(x);
    union { __hip_bfloat16 h; ushort u; } cv; cv.h = h;
    return cv.u;
}

// async global -> LDS, 16B per lane. lds dest = wave-uniform base (HW adds lane*16).
static __device__ __forceinline__ void gll16(const void* g, void* l) {
    __builtin_amdgcn_global_load_lds(
        (const __attribute__((address_space(1))) void*)g,
        (__attribute__((address_space(3))) void*)l, 16, 0, 0);
}

// ---------------- k0a: Wh f32 -> bf16, packed in MFMA B-fragment order ----------------
// whbp[((eb*32 + kb)*64 + lane)*8 + j] = bf16( Wh[eb*16 + (lane&15)][kb*32 + (lane>>4)*8 + j] )
__global__ __launch_bounds__(256) void kWhPack(const float* __restrict__ Wh,
                                               ushort* __restrict__ whbp) {
    int g = blockIdx.x * 256 + threadIdx.x;      // 131072 total
    int l  = g & 63;
    int kb = (g >> 6) & 31;
    int eb = g >> 11;
    int e  = eb * 16 + (l & 15);
    int k0 = kb * 32 + (l >> 4) * 8;
    const float* src = Wh + (size_t)e * DIM + k0;
    float4 a = *(const float4*)src;
    float4 b = *(const float4*)(src + 4);
    union { ushort us[8]; uint4 u4; } pk;
    pk.us[0] = f2bf(a.x); pk.us[1] = f2bf(a.y); pk.us[2] = f2bf(a.z); pk.us[3] = f2bf(a.w);
    pk.us[4] = f2bf(b.x); pk.us[5] = f2bf(b.y); pk.us[6] = f2bf(b.z); pk.us[7] = f2bf(b.w);
    *(uint4*)(whbp + (size_t)g * 8) = pk.u4;
}

// ---------------- k0b: base[b,e] = dec[b,:]·Ws[e,:] + bs + bh (+bc) ----------------
__global__ __launch_bounds__(256) void kBase(const float* __restrict__ dh,
                                             const float* __restrict__ Ws,
                                             const float* __restrict__ bs,
                                             const float* __restrict__ bh,
                                             const float* __restrict__ bc,
                                             const int* __restrict__ uc,
                                             float* __restrict__ base) {
    __shared__ float dec[8][DIM];
    int ec = blockIdx.x >> 2;
    int bg = blockIdx.x & 3;
    int b0 = bg * 8, e0 = ec * 32;
    int tid = threadIdx.x;
    for (int i = tid; i < 8 * DIM; i += 256) {
        int bb = i >> 10, d = i & 1023;
        float vdec = (d < 512) ? dh[(b0 + bb) * 512 + d]
                               : dh[BATCH * 512 + (b0 + bb) * 512 + d - 512];
        dec[bb][d] = vdec;
    }
    __syncthreads();
    int el = tid >> 3, ds = tid & 7;
    int e = e0 + el;
    float acc[8] = {0.f, 0.f, 0.f, 0.f, 0.f, 0.f, 0.f, 0.f};
    const float* wrow = Ws + (size_t)e * DIM;
    for (int i = 0; i < 128; ++i) {
        int d = i * 8 + ds;
        float wv = wrow[d];
#pragma unroll
        for (int bb = 0; bb < 8; ++bb) acc[bb] += wv * dec[bb][d];
    }
#pragma unroll
    for (int bb = 0; bb < 8; ++bb) {
        float s = acc[bb];
        s += __shfl_xor(s, 1); s += __shfl_xor(s, 2); s += __shfl_xor(s, 4);
        acc[bb] = s;
    }
    if (ds == 0) {
        float bias = bs[e] + bh[e] + ((*uc) ? bc[e] : 0.0f);
#pragma unroll
        for (int bb = 0; bb < 8; ++bb) base[(b0 + bb) * DIM + e] = acc[bb] + bias;
    }
}

// ---------------- k2: fused GEMM(bf16 MFMA) + tanh + v-dot -> partial score ----------------
// Block tile: M=128 rows x N=512 e-cols (nq half), K=1024, BK=32.
// 16 waves = 2(wm) x 8(wn); wave tile 64x64, acc[4][4].
// B staged into LDS via global_load_lds (dbuf, async across barrier); A f32->bf16 via regs.
// XCD pairing: blocks (rg,nq=0) and (rg,nq=1) are 8 apart in blockIdx -> same XCD L2.
__global__ __launch_bounds__(1024, 4) void kScore(const float* __restrict__ enc,
                                                  const ushort* __restrict__ whbp,
                                                  const float* __restrict__ base,
                                                  const float* __restrict__ pc,
                                                  const float* __restrict__ Wc,
                                                  const float* __restrict__ vv,
                                                  const int* __restrict__ uc,
                                                  float* __restrict__ scorep) {
    __shared__ ushort Bl[2][16384];   // [buf][eb_local*512 + lane*8], 32KB/buf
    __shared__ ushort Al[2][128 * 40]; // padded rows (40 ushort = 80B stride)
    __shared__ float pcl[128];
    __shared__ float red[16][64];

    const int tid = threadIdx.x;
    const int w = tid >> 6;
    const int lane = tid & 63;
    const int q = lane >> 4, l15 = lane & 15;
    const int wm = w >> 3, wn = w & 7;

    const int hb = blockIdx.x;                 // 1024 blocks
    const int nq = (hb >> 3) & 1;
    const int rg = ((hb >> 4) << 3) + (hb & 7); // [0,512)
    const int b = rg >> 4;
    const int s0 = (rg & 15) << 7;             // 128-row strip

    const float* Ab = enc + ((size_t)(b * SEQ + s0)) * DIM;
    if (tid < 128) pcl[tid] = pc[b * SEQ + s0 + tid];

    // A staging: thread -> (row = tid>>3, 4 f32 at k-offset (tid&7)*4)
    const int arow = tid >> 3, ak4 = (tid & 7) << 2;
    const float* agsrc = Ab + (size_t)arow * DIM + ak4;
    const int awidx = arow * 40 + ak4;          // ushort index, 8B-aligned

    // B staging: wave stages 2 frags/kt: eb_local = w*2 + {0,1}
    const int ebg0 = nq * 32 + w * 2;
    const ushort* bgsrc0 = whbp + ((size_t)(ebg0 + 0) << 14) + (lane << 3); // frag stride 32*512
    const ushort* bgsrc1 = whbp + ((size_t)(ebg0 + 1) << 14) + (lane << 3);
    ushort* bdst0_base0 = &Bl[0][(w * 2 + 0) * 512];
    ushort* bdst1_base0 = &Bl[0][(w * 2 + 1) * 512];

    f32x4 acc[4][4] = {};

    // prologue: stage kt=0 into buf 0
    {
        gll16(bgsrc0, bdst0_base0);
        gll16(bgsrc1, bdst1_base0);
        float4 a4 = *(const float4*)agsrc;
        u16x4 p; p[0] = f2bf(a4.x); p[1] = f2bf(a4.y); p[2] = f2bf(a4.z); p[3] = f2bf(a4.w);
        *(u16x4*)&Al[0][awidx] = p;
    }
    __syncthreads();

    int buf = 0;
    for (int kt = 0; kt < 32; ++kt) {
        float4 a4;
        if (kt < 31) {
            // async B stage for kt+1 into other buffer (overlaps MFMAs, drained at barrier)
            gll16(bgsrc0 + ((size_t)(kt + 1) << 9), &Bl[buf ^ 1][(w * 2 + 0) * 512]);
            gll16(bgsrc1 + ((size_t)(kt + 1) << 9), &Bl[buf ^ 1][(w * 2 + 1) * 512]);
            a4 = *(const float4*)(agsrc + (kt + 1) * 32);
        }
        // MFMA phase on buf
        short8 af[4], bf[4];
#pragma unroll
        for (int mf = 0; mf < 4; ++mf)
            af[mf] = *(const short8*)&Al[buf][(wm * 64 + mf * 16 + l15) * 40 + q * 8];
#pragma unroll
        for (int ef = 0; ef < 4; ++ef)
            bf[ef] = *(const short8*)&Bl[buf][(wn * 4 + ef) * 512 + lane * 8];
#pragma unroll
        for (int ef = 0; ef < 4; ++ef)
#pragma unroll
            for (int mf = 0; mf < 4; ++mf)
                acc[mf][ef] = __builtin_amdgcn_mfma_f32_16x16x32_bf16(af[mf], bf[ef], acc[mf][ef], 0, 0, 0);
        if (kt < 31) {
            u16x4 p; p[0] = f2bf(a4.x); p[1] = f2bf(a4.y); p[2] = f2bf(a4.z); p[3] = f2bf(a4.w);
            *(u16x4*)&Al[buf ^ 1][awidx] = p;
        }
        __syncthreads();   // drains vmcnt (B gll) + lgkm (A writes), flips pipeline
        buf ^= 1;
    }

    // epilogue: partial score = sum over this block's 512 e of tanh(acc+base+pc*Wc)*v
    const float ucf = (float)(*uc);
    float basee[4], ve[4], wce[4];
#pragma unroll
    for (int ef = 0; ef < 4; ++ef) {
        int e = nq * 512 + wn * 64 + ef * 16 + l15;
        basee[ef] = base[b * DIM + e];
        ve[ef] = vv[e];
        wce[ef] = Wc[e] * ucf;
    }
#pragma unroll
    for (int mf = 0; mf < 4; ++mf) {
#pragma unroll
        for (int r = 0; r < 4; ++r) {
            int rl = (mf << 4) + (q << 2) + r;          // row within wave's 64
            float p = pcl[wm * 64 + rl];
            float sp = 0.f;
#pragma unroll
            for (int ef = 0; ef < 4; ++ef) {
                float x = acc[mf][ef][r] + basee[ef] + p * wce[ef];
                float t = 1.0f - 2.0f / (1.0f + __expf(2.0f * x));  // tanh
                sp += t * ve[ef];
            }
            sp += __shfl_xor(sp, 1);
            sp += __shfl_xor(sp, 2);
            sp += __shfl_xor(sp, 4);
            sp += __shfl_xor(sp, 8);
            if (l15 == 0) red[w][rl] = sp;
        }
    }
    __syncthreads();
    if (tid < 128) {
        int wmf = tid >> 6, rl = tid & 63;
        float s = 0.f;
#pragma unroll
        for (int j = 0; j < 8; ++j) s += red[wmf * 8 + j][rl];
        scorep[nq * (BATCH * SEQ) + b * SEQ + s0 + tid] = s;  // bv dropped (softmax-invariant)
    }
}

// ---------------- k3: softmax (sum of 2 partials) + mask + renorm + coverage ----------------
__global__ __launch_bounds__(512) void kSoftmax(const float* __restrict__ scorep,
                                                const float* __restrict__ mask,
                                                const float* __restrict__ pc,
                                                float* __restrict__ att,
                                                float* __restrict__ cov,
                                                int write_cov) {
    __shared__ float rmax[8], rsum[8];
    int b = blockIdx.x, tid = threadIdx.x;
    int wv = tid >> 6, ln = tid & 63;
    float x[4];
#pragma unroll
    for (int i = 0; i < 4; ++i) {
        int idx = b * SEQ + tid + i * 512;
        x[i] = scorep[idx] + scorep[BATCH * SEQ + idx];
    }
    float m = fmaxf(fmaxf(x[0], x[1]), fmaxf(x[2], x[3]));
#pragma unroll
    for (int o = 1; o < 64; o <<= 1) m = fmaxf(m, __shfl_xor(m, o));
    if (ln == 0) rmax[wv] = m;
    __syncthreads();
    m = rmax[0];
#pragma unroll
    for (int i = 1; i < 8; ++i) m = fmaxf(m, rmax[i]);

    float ms[4], wm[4];
#pragma unroll
    for (int i = 0; i < 4; ++i) ms[i] = mask[b * SEQ + tid + i * 512];
    float s = 0.f;
#pragma unroll
    for (int i = 0; i < 4; ++i) { wm[i] = __expf(x[i] - m) * ms[i]; s += wm[i]; }
#pragma unroll
    for (int o = 1; o < 64; o <<= 1) s += __shfl_xor(s, o);
    if (ln == 0) rsum[wv] = s;
    __syncthreads();
    s = 0.f;
#pragma unroll
    for (int i = 0; i < 8; ++i) s += rsum[i];
    float inv = 1.0f / s;
#pragma unroll
    for (int i = 0; i < 4; ++i) {
        float wf = wm[i] * inv;
        att[b * SEQ + tid + i * 512] = wf;
        if (write_cov) cov[b * SEQ + tid + i * 512] = pc[b * SEQ + tid + i * 512] + wf;
    }
}

// ---------------- k4: context partials over s-chunks ----------------
__global__ __launch_bounds__(256) void kCtxPart(const float* __restrict__ enc,
                                                const float* __restrict__ att,
                                                float* __restrict__ part) {
    __shared__ float wl[64];
    int bx = blockIdx.x;           // 32 b x 32 s-chunks
    int b = bx >> 5, sc = bx & 31;
    int tid = threadIdx.x;
    if (tid < 64) wl[tid] = att[b * SEQ + sc * 64 + tid];
    __syncthreads();
    const float* basep = enc + ((size_t)(b * SEQ + sc * 64)) * DIM + tid * 4;
    float4 acc = {0.f, 0.f, 0.f, 0.f};
#pragma unroll 4
    for (int i = 0; i < 64; ++i) {
        float w = wl[i];
        float4 xv = *(const float4*)(basep + (size_t)i * DIM);
        acc.x += w * xv.x; acc.y += w * xv.y; acc.z += w * xv.z; acc.w += w * xv.w;
    }
    *(float4*)(part + (size_t)bx * DIM + tid * 4) = acc;
}

// ---------------- k5: deterministic reduce of partials ----------------
__global__ __launch_bounds__(256) void kCtxReduce(const float* __restrict__ part,
                                                  float* __restrict__ ctx) {
    int g = blockIdx.x * 256 + threadIdx.x;  // 32768
    int b = g >> 10, d = g & 1023;
    float s = 0.f;
#pragma unroll
    for (int i = 0; i < 32; ++i) s += part[((size_t)(b * 32 + i) << 10) + d];
    ctx[g] = s;
}

extern "C" void kernel_launch(void* const* d_in, const int* in_sizes, int n_in,
                              void* d_out, int out_size, void* d_ws, size_t ws_size,
                              hipStream_t stream) {
    const float* dh   = (const float*)d_in[0];
    const float* enc  = (const float*)d_in[1];
    const float* mask = (const float*)d_in[2];
    const float* pc   = (const float*)d_in[3];
    const float* Wh   = (const float*)d_in[4];
    const float* bh   = (const float*)d_in[5];
    const float* Ws   = (const float*)d_in[6];
    const float* bs   = (const float*)d_in[7];
    const float* Wc   = (const float*)d_in[8];
    const float* bc   = (const float*)d_in[9];
    const float* vv   = (const float*)d_in[10];
    // d_in[11] = bv: uniform shift of scores -> softmax-invariant -> unused
    const int* uc     = (const int*)d_in[12];

    float* ctx = (float*)d_out;
    float* att = ctx + BATCH * DIM;
    float* cov = att + BATCH * SEQ;
    int write_cov = (out_size >= BATCH * (DIM + 2 * SEQ)) ? 1 : 0;

    ushort* whbp  = (ushort*)d_ws;                                  // 2 MB (packed)
    float* base   = (float*)((char*)d_ws + 2u * 1024u * 1024u);     // 128 KB
    float* scorep = base + BATCH * DIM;                             // 512 KB (2 halves)
    float* part   = scorep + 2 * BATCH * SEQ;                       // 4 MB

    kWhPack<<<512, 256, 0, stream>>>(Wh, whbp);
    kBase<<<128, 256, 0, stream>>>(dh, Ws, bs, bh, bc, uc, base);
    kScore<<<1024, 1024, 0, stream>>>(enc, whbp, base, pc, Wc, vv, uc, scorep);
    kSoftmax<<<BATCH, 512, 0, stream>>>(scorep, mask, pc, att, cov, write_cov);
    kCtxPart<<<1024, 256, 0, stream>>>(enc, att, part);
    kCtxReduce<<<128, 256, 0, stream>>>(part, ctx);
}